// Round 9
// baseline (1351.412 us; speedup 1.0000x reference)
//
#include <hip/hip_runtime.h>
#include <math.h>

#define NN 50000
#define EE 800000
#define GG 2000
#define HH 128
#define FN 64
#define FE 16

typedef short bf16x8 __attribute__((ext_vector_type(8)));
typedef float f32x4  __attribute__((ext_vector_type(4)));

// ---------------- device helpers ----------------
__device__ __forceinline__ float leakyf(float v){ return v>=0.f ? v : 0.01f*v; }
__device__ __forceinline__ float eluf(float v){ return v>0.f ? v : expm1f(v); }
__device__ __forceinline__ float sigmf(float v){ return 1.f/(1.f+__expf(-v)); }
__device__ __forceinline__ float tanh_fast(float x){
  float ax = fabsf(x);
  float e = __expf(-2.f*ax);
  float t = (1.f - e)/(1.f + e);
  return x>=0.f ? t : -t;
}
__device__ __forceinline__ int rdl(int v, int l){ return __builtin_amdgcn_readlane(v, l); }
__device__ __forceinline__ float rdlf(float v, int l){
  return __int_as_float(__builtin_amdgcn_readlane(__float_as_int(v), l));
}
__device__ __forceinline__ float wsum(float v){
#pragma unroll
  for(int m=32;m>=1;m>>=1) v += __shfl_xor(v,m,64);
  return v;
}
__device__ __forceinline__ float wsum16(float v){
#pragma unroll
  for(int m=8;m>=1;m>>=1) v += __shfl_xor(v,m,64);
  return v;
}
__device__ __forceinline__ float wmax64(float v){
#pragma unroll
  for(int m=32;m>=1;m>>=1) v = fmaxf(v,__shfl_xor(v,m,64));
  return v;
}

__device__ __forceinline__ f32x4 mfma16(bf16x8 a, bf16x8 b, f32x4 c){
  return __builtin_amdgcn_mfma_f32_16x16x32_bf16(a, b, c, 0, 0, 0);
}

// split 8 consecutive fp32 into bf16 hi (truncate) + bf16 lo (truncate of residual)
__device__ __forceinline__ void splitbf8(const float* p, bf16x8 &hi, bf16x8 &lo){
  float4 u = *(const float4*)p;
  float4 v = *(const float4*)(p+4);
  float f[8] = {u.x,u.y,u.z,u.w,v.x,v.y,v.z,v.w};
#pragma unroll
  for(int i=0;i<8;i++){
    unsigned b = __float_as_uint(f[i]);
    unsigned ht = b & 0xFFFF0000u;
    hi[i] = (short)(b >> 16);
    float r = f[i] - __uint_as_float(ht);
    lo[i] = (short)(__float_as_uint(r) >> 16);
  }
}

// ---------------- weight pre-split segment map (elements) ----------------
#define CV_LIN1   0        // 128x64
#define CV_G1X    8192     // 128x128 from glin1W (ld 144, cols 0..127)
#define CV_G2     24576    // 128x128
#define CV_ALIN   40960    // 2x128x128
#define CV_MOL    73728    // 128x128
#define CV_G0IH   90112    // 384x128
#define CV_G0HH   139264
#define CV_AIH    188416   // 2x384x128
#define CV_AHH    286720
#define CV_MIH    385024
#define CV_MHH    434176
#define CV_GE     483328   // 128x16: glin1W edge-part (cols 128..143)
#define CV_TOT2   485376

__global__ void k_convw2(const float* __restrict__ lin1W, const float* __restrict__ glin1W,
                         const float* __restrict__ glin2W, const float* __restrict__ aLinW,
                         const float* __restrict__ aGWih, const float* __restrict__ aGWhh,
                         const float* __restrict__ mLinW, const float* __restrict__ mGWih,
                         const float* __restrict__ mGWhh, const float* __restrict__ g0Wih,
                         const float* __restrict__ g0Whh,
                         short* __restrict__ hi, short* __restrict__ lo){
  int i = blockIdx.x*256 + threadIdx.x;
  if(i >= CV_TOT2) return;
  float v;
  if(i < CV_G1X){            v = lin1W[i];
  } else if(i < CV_G2){      int idx = i - CV_G1X; v = glin1W[(size_t)(idx>>7)*144 + (idx&127)];
  } else if(i < CV_ALIN){    v = glin2W[i - CV_G2];
  } else if(i < CV_MOL){     v = aLinW[i - CV_ALIN];
  } else if(i < CV_G0IH){    v = mLinW[i - CV_MOL];
  } else if(i < CV_G0HH){    v = g0Wih[i - CV_G0IH];
  } else if(i < CV_AIH){     v = g0Whh[i - CV_G0HH];
  } else if(i < CV_AHH){     v = aGWih[i - CV_AIH];
  } else if(i < CV_MIH){     v = aGWhh[i - CV_AHH];
  } else if(i < CV_MHH){     v = mGWih[i - CV_MIH];
  } else if(i < CV_GE){      v = mGWhh[i - CV_MHH];
  } else {                   int idx = i - CV_GE; v = glin1W[(size_t)(idx>>4)*144 + 128 + (idx&15)];
  }
  unsigned b = __float_as_uint(v);
  unsigned ht = b & 0xFFFF0000u;
  hi[i] = (short)(b >> 16);
  float r = v - __uint_as_float(ht);
  lo[i] = (short)(__float_as_uint(r) >> 16);
}

// ---------------- CSR build (fused: both edge sorts + graph counts) ----------------
__global__ void k_count_all(const int* __restrict__ esrc, const int* __restrict__ edst,
                            const int* __restrict__ batch,
                            int* __restrict__ degd, int* __restrict__ degs,
                            int* __restrict__ gcnt){
  int i = blockIdx.x*256 + threadIdx.x;
  if(i < EE){
    atomicAdd(&degd[edst[i]], 1);
    atomicAdd(&degs[esrc[i]], 1);
  }
  if(i < NN) atomicAdd(&gcnt[batch[i]], 1);
}

__global__ void k_scan3(const int* __restrict__ degd, const int* __restrict__ degs,
                        const int* __restrict__ gcnt,
                        int* __restrict__ eoff, int* __restrict__ soff, int* __restrict__ goff){
  __shared__ int part[1024];
  const int* cnt; int* off; int n;
  if(blockIdx.x == 0){ cnt = degd; off = eoff; n = NN; }
  else if(blockIdx.x == 1){ cnt = degs; off = soff; n = NN; }
  else { cnt = gcnt; off = goff; n = GG; }
  int t = threadIdx.x;
  int C = (n + 1023) >> 10;
  int lo = t*C, hic = min(lo + C, n);
  int s = 0;
  for(int i=lo;i<hic;i++) s += cnt[i];
  part[t] = s;
  __syncthreads();
  for(int o=1;o<1024;o<<=1){
    int v = (t>=o) ? part[t-o] : 0;
    __syncthreads();
    part[t] += v;
    __syncthreads();
  }
  int base = part[t] - s;
  int run = base;
  for(int i=lo;i<hic;i++){ run += cnt[i]; off[i+1] = run; }
  if(t==0) off[0] = 0;
}

__global__ void k_scatter2(const int* __restrict__ esrc, const int* __restrict__ edst,
                           const int* __restrict__ eoff, const int* __restrict__ soff,
                           int* __restrict__ curd, int* __restrict__ curs,
                           int* __restrict__ esrcS, int* __restrict__ eperm,
                           int* __restrict__ eord){
  int e = blockIdx.x*256 + threadIdx.x;
  if(e < EE){
    int d = edst[e];
    int pos = eoff[d] + atomicAdd(&curd[d], 1);
    esrcS[pos] = esrc[e];
    eperm[e] = pos;
    int s = esrc[e];
    int pos2 = soff[s] + atomicAdd(&curs[s], 1);
    eord[pos2] = e;
  }
}

// ---------------- MFMA projection + fused row-dots ----------------
template<int ACT, int K, int NDOT>
__global__ __launch_bounds__(256) void k_proj_mfma(const float* __restrict__ A,
                                                   const short* __restrict__ Whi,
                                                   const short* __restrict__ Wlo,
                                                   const float* __restrict__ bias,
                                                   float* __restrict__ C, int M,
                                                   const float* __restrict__ u,
                                                   const float* __restrict__ v,
                                                   float* __restrict__ douta,
                                                   float* __restrict__ doutb){
  const int wave = threadIdx.x >> 6, lane = threadIdx.x & 63;
  const int m0 = blockIdx.x*64 + wave*16;
  const int lr = lane & 15, kg = lane >> 4;
  f32x4 acc[8];
#pragma unroll
  for(int t=0;t<8;t++) acc[t] = (f32x4){0.f,0.f,0.f,0.f};

  int arow = m0 + lr;
  int ar = arow < M ? arow : (M-1);

#pragma unroll
  for(int ks=0;ks<K;ks+=32){
    const int kb = ks + kg*8;
    bf16x8 ahi, alo;
    splitbf8(&A[(size_t)ar*K + kb], ahi, alo);
#pragma unroll
    for(int t=0;t<8;t++){
      const bf16x8 bh = *(const bf16x8*)&Whi[(size_t)(t*16+lr)*K + kb];
      const bf16x8 bl = *(const bf16x8*)&Wlo[(size_t)(t*16+lr)*K + kb];
      acc[t] = mfma16(ahi, bh, acc[t]);
      acc[t] = mfma16(ahi, bl, acc[t]);
      acc[t] = mfma16(alo, bh, acc[t]);
    }
  }

  float p1[4] = {0.f,0.f,0.f,0.f};
  float p2[4] = {0.f,0.f,0.f,0.f};
#pragma unroll
  for(int t=0;t<8;t++){
    int c = t*16 + lr;
    float ut = (NDOT>=1) ? u[c] : 0.f;
    float vt = (NDOT>=2) ? v[c] : 0.f;
#pragma unroll
    for(int r=0;r<4;r++){
      int m = m0 + kg*4 + r;
      float val = acc[t][r];
      if(ACT==1) val = leakyf(val + bias[c]);
      if(m < M) C[(size_t)m*HH + c] = val;
      if(NDOT>=1) p1[r] += val*ut;
      if(NDOT>=2) p2[r] += val*vt;
    }
  }
  if(NDOT>=1){
#pragma unroll
    for(int r=0;r<4;r++){
      float s1 = wsum16(p1[r]);
      int m = m0 + kg*4 + r;
      if(lr==0 && m < M) douta[m] = s1;
      if(NDOT>=2){
        float s2 = wsum16(p2[r]);
        if(lr==0 && m < M) doutb[m] = s2;
      }
    }
  }
}

// ---------------- fused MFMA GRUCell v3: LDS-staged weights (r7-verified) ----------------
__global__ __launch_bounds__(256) void k_gru_mfma(const float* __restrict__ MSG,
                                                  const float* __restrict__ X,
                                                  const short* __restrict__ WIhi,
                                                  const short* __restrict__ WIlo,
                                                  const short* __restrict__ WHhi,
                                                  const short* __restrict__ WHlo,
                                                  const float* __restrict__ bih,
                                                  const float* __restrict__ bhh,
                                                  float* __restrict__ XOUT, int M){
  __shared__ short LW[12*16*128];
  const int tid = threadIdx.x;
  const int wave = tid >> 6, lane = tid & 63;
  const int m0 = blockIdx.x*64 + wave*16;
  const int lr = lane & 15, kg = lane >> 4;
  int arow = m0 + lr;
  int ar = arow < M ? arow : (M-1);

  bf16x8 mh[4], ml[4], xh[4], xl[4];
#pragma unroll
  for(int ks=0;ks<4;ks++){
    splitbf8(&MSG[(size_t)ar*HH + ks*32 + kg*8], mh[ks], ml[ks]);
    splitbf8(&X  [(size_t)ar*HH + ks*32 + kg*8], xh[ks], xl[ks]);
  }

  const int srow = tid >> 4;
  const int scb  = tid & 15;
  const int sdst = srow*128 + ((scb ^ (srow & 7))*8);
  const size_t sgoff = (size_t)srow*HH + scb*8;

#pragma unroll 1
  for(int t=0;t<8;t++){
#pragma unroll
    for(int r=0;r<12;r++){
      const short* mat = (r<3) ? WIhi : (r<6) ? WHhi : (r<9) ? WIlo : WHlo;
      const int g = (r % 3);
      const short* src = mat + (size_t)(g*128 + t*16)*HH + sgoff;
      *(bf16x8*)&LW[r*2048 + sdst] = *(const bf16x8*)src;
    }
    __syncthreads();

    f32x4 aIr = (f32x4){0.f,0.f,0.f,0.f}, aIz = aIr, aIn = aIr;
    f32x4 aHr = aIr, aHz = aIr, aHn = aIr;
#pragma unroll
    for(int ks=0;ks<4;ks++){
      const int cb = ks*4 + kg;
      const int rb = lr*128 + ((cb ^ (lr & 7))*8);
      bf16x8 bIrh = *(const bf16x8*)&LW[ 0*2048 + rb];
      bf16x8 bIzh = *(const bf16x8*)&LW[ 1*2048 + rb];
      bf16x8 bInh = *(const bf16x8*)&LW[ 2*2048 + rb];
      bf16x8 bHrh = *(const bf16x8*)&LW[ 3*2048 + rb];
      bf16x8 bHzh = *(const bf16x8*)&LW[ 4*2048 + rb];
      bf16x8 bHnh = *(const bf16x8*)&LW[ 5*2048 + rb];
      bf16x8 bIrl = *(const bf16x8*)&LW[ 6*2048 + rb];
      bf16x8 bIzl = *(const bf16x8*)&LW[ 7*2048 + rb];
      bf16x8 bInl = *(const bf16x8*)&LW[ 8*2048 + rb];
      bf16x8 bHrl = *(const bf16x8*)&LW[ 9*2048 + rb];
      bf16x8 bHzl = *(const bf16x8*)&LW[10*2048 + rb];
      bf16x8 bHnl = *(const bf16x8*)&LW[11*2048 + rb];
      aIr = mfma16(mh[ks], bIrh, aIr); aIr = mfma16(mh[ks], bIrl, aIr); aIr = mfma16(ml[ks], bIrh, aIr);
      aIz = mfma16(mh[ks], bIzh, aIz); aIz = mfma16(mh[ks], bIzl, aIz); aIz = mfma16(ml[ks], bIzh, aIz);
      aIn = mfma16(mh[ks], bInh, aIn); aIn = mfma16(mh[ks], bInl, aIn); aIn = mfma16(ml[ks], bInh, aIn);
      aHr = mfma16(xh[ks], bHrh, aHr); aHr = mfma16(xh[ks], bHrl, aHr); aHr = mfma16(xl[ks], bHrh, aHr);
      aHz = mfma16(xh[ks], bHzh, aHz); aHz = mfma16(xh[ks], bHzl, aHz); aHz = mfma16(xl[ks], bHzh, aHz);
      aHn = mfma16(xh[ks], bHnh, aHn); aHn = mfma16(xh[ks], bHnl, aHn); aHn = mfma16(xl[ks], bHnh, aHn);
    }

    const int c = t*16 + lr;
    const float bir = bih[c], biz = bih[c+HH], bin = bih[c+2*HH];
    const float bhr = bhh[c], bhz = bhh[c+HH], bhn = bhh[c+2*HH];
#pragma unroll
    for(int r=0;r<4;r++){
      int mm = m0 + kg*4 + r;
      if(mm < M){
        float ir = aIr[r]+bir, iz = aIz[r]+biz, in_ = aIn[r]+bin;
        float hr = aHr[r]+bhr, hz = aHz[r]+bhz, hn = aHn[r]+bhn;
        float rr = sigmf(ir + hr);
        float z  = sigmf(iz + hz);
        float ng = tanh_fast(in_ + rr*hn);
        float hp = X[(size_t)mm*HH + c];
        XOUT[(size_t)mm*HH + c] = fmaxf((1.f - z)*ng + z*hp, 0.f);
      }
    }
    __syncthreads();
  }
}

// ---------------- GATEConv edge alpha v4: MFMA over 16-edge tiles ----------------
// R7 diagnosis: alpha3 was LDS-issue bound (2048 ds_read_b32/edge for W1E).
// Fix: eaw = ea @ W1e^T via MFMA with Markidis split packed into K=32:
//   MFMA1: A=[ea_hi(k0..15)|ea_lo(k16..31)], B=[w_hi|w_hi] -> hi*hi + lo*hi
//   MFMA2: A=[ea_hi|0],                      B=[w_lo|...]  -> hi*lo
// C/D layout: col=lane&15, row(edge)=kg*4+r. Epilogue: + XP[src] gather (src-sorted
// -> L1 reuse), leaky, *attl, wsum16 over cols, + RD[dst], scatter to ALPHA[perm].
__global__ __launch_bounds__(256) void k_gate_alpha4(const float* __restrict__ XP,
                                                     const float* __restrict__ EA,
                                                     const int* __restrict__ esrc,
                                                     const int* __restrict__ edst,
                                                     const short* __restrict__ GEhi,
                                                     const short* __restrict__ GElo,
                                                     const float* __restrict__ attl,
                                                     const float* __restrict__ RD,
                                                     const int* __restrict__ eperm,
                                                     const int* __restrict__ eord,
                                                     float* __restrict__ ALPHA){
  const int lane = threadIdx.x & 63;
  const int wid = (blockIdx.x*256 + threadIdx.x) >> 6;
  if(wid >= EE/128) return;                 // 6250 waves, 8 tiles (128 edges) each
  const int lr = lane & 15, kg = lane >> 4;

  // B-frags for 8 col-tiles (loaded once per wave)
  bf16x8 B1[8], B2[8];
#pragma unroll
  for(int t=0;t<8;t++){
    const int col = t*16 + lr;
    B1[t] = *(const bf16x8*)&GEhi[col*16 + (kg&1)*8];
    B2[t] = *(const bf16x8*)&GElo[col*16 + (kg&1)*8];
  }
  float at[8];
#pragma unroll
  for(int t=0;t<8;t++) at[t] = attl[t*16 + lr];

#pragma unroll 1
  for(int tw = wid*8; tw < wid*8 + 8; ++tw){
    const int p0 = tw*16;
    // A-frags: lane holds ea chunk (kg&1)*8 of its row's edge; hi for kg<2, lo for kg>=2
    const int eoA = eord[p0 + lr];
    bf16x8 hi8, lo8;
    splitbf8(&EA[(size_t)eoA*FE + (kg&1)*8], hi8, lo8);
    bf16x8 A1 = (kg < 2) ? hi8 : lo8;
    bf16x8 A2 = hi8;
    if(kg >= 2){
#pragma unroll
      for(int i=0;i<8;i++) A2[i] = 0;
    }
    // rows this lane epilogues: edge j = kg*4+r
    int srcR[4];
#pragma unroll
    for(int r=0;r<4;r++) srcR[r] = esrc[eord[p0 + kg*4 + r]];

    float p[4] = {0.f,0.f,0.f,0.f};
#pragma unroll
    for(int t=0;t<8;t++){
      f32x4 acc = (f32x4){0.f,0.f,0.f,0.f};
      acc = mfma16(A2, B2[t], acc);
      acc = mfma16(A1, B1[t], acc);
      const int c = t*16 + lr;
#pragma unroll
      for(int r=0;r<4;r++){
        float xp = XP[(size_t)srcR[r]*HH + c];
        p[r] += leakyf(acc[r] + xp) * at[t];
      }
    }
#pragma unroll
    for(int r=0;r<4;r++){
      float s = wsum16(p[r]);
      if(lr == 0){
        const int eoj = eord[p0 + kg*4 + r];
        ALPHA[eperm[eoj]] = leakyf(s + RD[edst[eoj]]);
      }
    }
  }
}

// ---------------- segment softmax -> normalized edge weights ----------------
template<int MODE>
__global__ void k_softmaxw(const int* __restrict__ off, const int* __restrict__ items,
                           const float* __restrict__ AIN, const float* __restrict__ A1,
                           const float* __restrict__ A2, float* __restrict__ WOUT, int nseg){
  int w = (blockIdx.x*blockDim.x + threadIdx.x) >> 6;
  int lane = threadIdx.x & 63;
  if(w >= nseg) return;
  int s0 = off[w], s1 = off[w+1];
  int n = s1 - s0;
  float a2 = (MODE==0) ? 0.f : A2[w];

  if(n <= 64){
    float a = -INFINITY;
    int i = s0 + lane;
    if(lane < n){
      if(MODE==0) a = AIN[i];
      else if(MODE==1) a = leakyf(A1[items[i]] + a2);
      else a = leakyf(A1[i] + a2);
    }
    float m = wmax64(a);
    float e = (lane < n) ? __expf(a - m) : 0.f;
    float s = wsum(e);
    if(lane < n) WOUT[i] = e/(s + 1e-16f);
    return;
  }

  float m = -INFINITY;
  for(int i=s0+lane;i<s1;i+=64){
    float a;
    if(MODE==0) a = AIN[i];
    else if(MODE==1) a = leakyf(A1[items[i]] + a2);
    else a = leakyf(A1[i] + a2);
    m = fmaxf(m, a);
  }
  m = wmax64(m);

  float s = 0.f;
  for(int i=s0+lane;i<s1;i+=64){
    float a;
    if(MODE==0) a = AIN[i];
    else if(MODE==1) a = leakyf(A1[items[i]] + a2);
    else a = leakyf(A1[i] + a2);
    s += __expf(a - m);
  }
  s = wsum(s);
  float inv = 1.f/(s + 1e-16f);

  for(int i=s0+lane;i<s1;i+=64){
    float a;
    if(MODE==0) a = AIN[i];
    else if(MODE==1) a = leakyf(A1[items[i]] + a2);
    else a = leakyf(A1[i] + a2);
    WOUT[i] = __expf(a - m)*inv;
  }
}

// ---------------- weighted row gather: OUT[w] = elu(sum_i W[i]*XSrc[it_i] + bias) ----------------
__global__ void k_gather(const int* __restrict__ off, const int* __restrict__ items,
                         const float* __restrict__ W, const float* __restrict__ XSrc,
                         const float* __restrict__ bias, float* __restrict__ OUT, int nseg){
  int w = (blockIdx.x*blockDim.x + threadIdx.x) >> 6;
  int lane = threadIdx.x & 63;
  if(w >= nseg) return;
  int s0 = off[w], s1 = off[w+1];
  float hx = 0.f, hy = 0.f;

  for(int c0=s0;c0<s1;c0+=64){
    int n = min(64, s1-c0);
    int it = 0; float wg = 0.f;
    if(lane < n){
      int i = c0 + lane;
      it = items ? items[i] : i;
      wg = W[i];
    }
#pragma unroll 16
    for(int j=0;j<n;j++){
      int itj = rdl(it, j);
      float wj = rdlf(wg, j);
      float2 xv = *(const float2*)&XSrc[(size_t)itj*HH + 2*lane];
      hx += wj*xv.x;
      hy += wj*xv.y;
    }
  }
  float2 bv = *(const float2*)&bias[2*lane];
  float2 o;
  o.x = eluf(hx + bv.x);
  o.y = eluf(hy + bv.y);
  *(float2*)&OUT[(size_t)w*HH + 2*lane] = o;
}

// ---------------- small per-row kernels ----------------
__global__ void k_dot2(const float* __restrict__ X, const float* __restrict__ u,
                       float* __restrict__ a, int M){
  int w = (blockIdx.x*blockDim.x + threadIdx.x) >> 6;
  int lane = threadIdx.x & 63;
  if(w >= M) return;
  float2 x = *(const float2*)&X[(size_t)w*HH + 2*lane];
  float2 uu = *(const float2*)&u[2*lane];
  float p = x.x*uu.x + x.y*uu.y;
  p = wsum(p);
  if(lane==0) a[w] = p;
}

__global__ void k_ginit(const int* __restrict__ goff, const float* __restrict__ X,
                        float* __restrict__ OUT){
  int g = (blockIdx.x*blockDim.x + threadIdx.x) >> 6;
  int lane = threadIdx.x & 63;
  if(g >= GG) return;
  int s0 = goff[g], s1 = goff[g+1];
  float hx=0.f, hy=0.f;
  for(int n=s0;n<s1;n++){
    float2 xv = *(const float2*)&X[(size_t)n*HH + 2*lane];
    hx += xv.x; hy += xv.y;
  }
  float2 o;
  o.x = fmaxf(hx, 0.f);
  o.y = fmaxf(hy, 0.f);
  *(float2*)&OUT[(size_t)g*HH + 2*lane] = o;
}

// weff[c] = finW·lin2W[:,c]; weff[128] = lin2b·finW + finb; weff[256+c] = mAttD·mLinW[:,c]
__global__ void k_weff(const float* __restrict__ lin2W, const float* __restrict__ lin2b,
                       const float* __restrict__ finW, const float* __restrict__ finb,
                       const float* __restrict__ mLinW, const float* __restrict__ mAttD,
                       float* __restrict__ weff){
  int c = threadIdx.x;
  float s = 0.f, q = 0.f;
  for(int j=0;j<HH;j++){
    s += finW[j]*lin2W[(size_t)j*HH + c];
    q += mAttD[j]*mLinW[(size_t)j*HH + c];
  }
  weff[c] = s;
  weff[256 + c] = q;
  if(c==0){
    float bb = finb[0];
    for(int j=0;j<HH;j++) bb += lin2b[j]*finW[j];
    weff[HH] = bb;
  }
}

__global__ void k_final(const float* __restrict__ OUT, const float* __restrict__ weff,
                        float* __restrict__ y){
  int g = (blockIdx.x*blockDim.x + threadIdx.x) >> 6;
  int lane = threadIdx.x & 63;
  if(g >= GG) return;
  float2 ov = *(const float2*)&OUT[(size_t)g*HH + 2*lane];
  float2 wv = *(const float2*)&weff[2*lane];
  float p = ov.x*wv.x + ov.y*wv.y;
  p = wsum(p);
  if(lane==0) y[g] = sigmf(p + weff[HH]);
}

// ---------------- host ----------------
extern "C" void kernel_launch(void* const* d_in, const int* in_sizes, int n_in,
                              void* d_out, int out_size, void* d_ws, size_t ws_size,
                              hipStream_t stream){
  const float* in_x   = (const float*)d_in[0];
  const int*   eidx   = (const int*)d_in[1];
  const float* ea     = (const float*)d_in[2];
  const int*   batch  = (const int*)d_in[3];
  const float* lin1W  = (const float*)d_in[4];
  const float* lin1b  = (const float*)d_in[5];
  const float* gattl  = (const float*)d_in[6];
  const float* gattr  = (const float*)d_in[7];
  const float* glin1W = (const float*)d_in[8];
  const float* glin2W = (const float*)d_in[9];
  const float* gbias  = (const float*)d_in[10];
  const float* g0Wih  = (const float*)d_in[11];
  const float* g0Whh  = (const float*)d_in[12];
  const float* g0bih  = (const float*)d_in[13];
  const float* g0bhh  = (const float*)d_in[14];
  const float* aLinW  = (const float*)d_in[15];
  const float* aAttS  = (const float*)d_in[16];
  const float* aAttD  = (const float*)d_in[17];
  const float* aBias  = (const float*)d_in[18];
  const float* aGWih  = (const float*)d_in[19];
  const float* aGWhh  = (const float*)d_in[20];
  const float* aGbih  = (const float*)d_in[21];
  const float* aGbhh  = (const float*)d_in[22];
  const float* mLinW  = (const float*)d_in[23];
  const float* mAttS  = (const float*)d_in[24];
  const float* mAttD  = (const float*)d_in[25];
  const float* mBias  = (const float*)d_in[26];
  const float* mGWih  = (const float*)d_in[27];
  const float* mGWhh  = (const float*)d_in[28];
  const float* mGbih  = (const float*)d_in[29];
  const float* mGbhh  = (const float*)d_in[30];
  const float* lin2W  = (const float*)d_in[31];
  const float* lin2b  = (const float*)d_in[32];
  const float* finW   = (const float*)d_in[33];
  const float* finb   = (const float*)d_in[34];

  const int* esrc0 = eidx;
  const int* edst0 = eidx + EE;

  char* w = (char*)d_ws;
  size_t o = 0;
  auto alloc = [&](size_t bytes)->void*{
    void* p = w + o;
    o = (o + bytes + 255) & ~(size_t)255;
    return p;
  };
  float* X    = (float*)alloc((size_t)NN*HH*4);
  float* XB   = (float*)alloc((size_t)NN*HH*4);
  float* XS   = (float*)alloc((size_t)NN*HH*4);
  float* MSG  = (float*)alloc((size_t)NN*HH*4);
  float* XP   = (float*)alloc((size_t)NN*HH*4);
  float* ALPHA= (float*)alloc((size_t)EE*4);
  float* S1   = (float*)alloc((size_t)NN*4);
  float* S2   = (float*)alloc((size_t)NN*4);
  float* ADSTG= (float*)alloc((size_t)GG*4);
  float* OUTg = (float*)alloc((size_t)GG*HH*4);
  float* OUTb = (float*)alloc((size_t)GG*HH*4);
  float* HG   = (float*)alloc((size_t)GG*HH*4);
  float* WEFF = (float*)alloc(512*4);
  short* cWhi = (short*)alloc((size_t)CV_TOT2*2);
  short* cWlo = (short*)alloc((size_t)CV_TOT2*2);
  int* zeroreg= (int*)alloc((size_t)(4*NN + 2048)*4);
  int* degd = zeroreg;
  int* degs = zeroreg + NN;
  int* curd = zeroreg + 2*NN;
  int* curs = zeroreg + 3*NN;
  int* gcnt = zeroreg + 4*NN;
  int* eoff = (int*)alloc((size_t)(NN+1)*4);
  int* soff = (int*)alloc((size_t)(NN+1)*4);
  int* goff = (int*)alloc((size_t)(GG+1)*4);
  int* esrcS= (int*)alloc((size_t)EE*4);
  int* eperm= (int*)alloc((size_t)EE*4);
  int* eord = (int*)alloc((size_t)EE*4);

  const short* c_lin1_h = cWhi + CV_LIN1; const short* c_lin1_l = cWlo + CV_LIN1;
  const short* c_g1x_h  = cWhi + CV_G1X;  const short* c_g1x_l  = cWlo + CV_G1X;
  const short* c_g2_h   = cWhi + CV_G2;   const short* c_g2_l   = cWlo + CV_G2;
  const short* c_mol_h  = cWhi + CV_MOL;  const short* c_mol_l  = cWlo + CV_MOL;
  const short* c_g0ih_h = cWhi + CV_G0IH; const short* c_g0ih_l = cWlo + CV_G0IH;
  const short* c_g0hh_h = cWhi + CV_G0HH; const short* c_g0hh_l = cWlo + CV_G0HH;
  const short* c_mih_h  = cWhi + CV_MIH;  const short* c_mih_l  = cWlo + CV_MIH;
  const short* c_mhh_h  = cWhi + CV_MHH;  const short* c_mhh_l  = cWlo + CV_MHH;
  const short* c_ge_h   = cWhi + CV_GE;   const short* c_ge_l   = cWlo + CV_GE;

  // ---- weight pre-split + fused final-layer vectors ----
  k_convw2<<<(CV_TOT2+255)/256, 256, 0, stream>>>(lin1W, glin1W, glin2W, aLinW, aGWih, aGWhh,
                                                  mLinW, mGWih, mGWhh, g0Wih, g0Whh, cWhi, cWlo);
  k_weff<<<1, 128, 0, stream>>>(lin2W, lin2b, finW, finb, mLinW, mAttD, WEFF);

  // ---- CSR build (dst-sorted + src-sorted + graph offsets) ----
  hipMemsetAsync(zeroreg, 0, (size_t)(4*NN + 2048)*4, stream);
  k_count_all<<<EE/256, 256, 0, stream>>>(esrc0, edst0, batch, degd, degs, gcnt);
  k_scan3<<<3, 1024, 0, stream>>>(degd, degs, gcnt, eoff, soff, goff);
  k_scatter2<<<EE/256, 256, 0, stream>>>(esrc0, edst0, eoff, soff, curd, curs, esrcS, eperm, eord);

  const int gN = (NN + 63)/64;   // 782
  const int gG = (GG + 63)/64;   // 32

  // ---- input projection (+ fused S1 = X·gattr) ----
  k_proj_mfma<1,64,1><<<gN, 256, 0, stream>>>(in_x, c_lin1_h, c_lin1_l, lin1b, X, NN,
                                              gattr, nullptr, S1, nullptr);

  // ---- GATEConv ----
  k_proj_mfma<0,128,0><<<gN, 256, 0, stream>>>(X, c_g1x_h, c_g1x_l, nullptr, XP, NN,
                                               nullptr, nullptr, nullptr, nullptr);
  k_proj_mfma<0,128,0><<<gN, 256, 0, stream>>>(X, c_g2_h, c_g2_l, nullptr, XS, NN,
                                               nullptr, nullptr, nullptr, nullptr);
  k_gate_alpha4<<<(EE/128 + 3)/4, 256, 0, stream>>>(XP, ea, esrc0, edst0, c_ge_h, c_ge_l,
                                                    gattl, S1, eperm, eord, ALPHA);
  k_softmaxw<0><<<(NN+3)/4, 256, 0, stream>>>(eoff, nullptr, ALPHA, nullptr, nullptr, ALPHA, NN);
  k_gather<<<(NN+3)/4, 256, 0, stream>>>(eoff, esrcS, ALPHA, XS, gbias, MSG, NN);
  k_gru_mfma<<<gN, 256, 0, stream>>>(MSG, X, c_g0ih_h, c_g0ih_l, c_g0hh_h, c_g0hh_l,
                                     g0bih, g0bhh, XB, NN);
  { float* t = X; X = XB; XB = t; }

  // ---- atom GATConv layers ----
  for(int l=0;l<2;l++){
    const short* c_a_h   = cWhi + CV_ALIN + (size_t)l*HH*HH;
    const short* c_a_l   = cWlo + CV_ALIN + (size_t)l*HH*HH;
    const short* c_aih_h = cWhi + CV_AIH + (size_t)l*3*HH*HH;
    const short* c_aih_l = cWlo + CV_AIH + (size_t)l*3*HH*HH;
    const short* c_ahh_h = cWhi + CV_AHH + (size_t)l*3*HH*HH;
    const short* c_ahh_l = cWlo + CV_AHH + (size_t)l*3*HH*HH;
    const float* asl  = aAttS + (size_t)l*HH;
    const float* adl  = aAttD + (size_t)l*HH;
    const float* bl   = aBias + (size_t)l*HH;
    const float* bi   = aGbih + (size_t)l*3*HH;
    const float* bh   = aGbhh + (size_t)l*3*HH;
    k_proj_mfma<0,128,2><<<gN, 256, 0, stream>>>(X, c_a_h, c_a_l, nullptr, XS, NN,
                                                 asl, adl, S1, S2);
    k_softmaxw<1><<<(NN+3)/4, 256, 0, stream>>>(eoff, esrcS, nullptr, S1, S2, ALPHA, NN);
    k_gather<<<(NN+3)/4, 256, 0, stream>>>(eoff, esrcS, ALPHA, XS, bl, MSG, NN);
    k_gru_mfma<<<gN, 256, 0, stream>>>(MSG, X, c_aih_h, c_aih_l, c_ahh_h, c_ahh_l, bi, bh, XB, NN);
    { float* t = X; X = XB; XB = t; }
  }

  // ---- molecule readout ----
  k_ginit<<<(GG+3)/4, 256, 0, stream>>>(goff, X, OUTg);
  k_proj_mfma<0,128,1><<<gN, 256, 0, stream>>>(X, c_mol_h, c_mol_l, nullptr, XS, NN,
                                               mAttS, nullptr, S1, nullptr);

  float* Ocur = OUTg;
  float* Onxt = OUTb;
  for(int t=0;t<3;t++){
    k_dot2<<<(GG+3)/4, 256, 0, stream>>>(Ocur, WEFF+256, ADSTG, GG);
    k_softmaxw<2><<<(GG+3)/4, 256, 0, stream>>>(goff, nullptr, nullptr, S1, ADSTG, ALPHA, GG);
    k_gather<<<(GG+3)/4, 256, 0, stream>>>(goff, nullptr, ALPHA, XS, mBias, HG, GG);
    k_gru_mfma<<<gG, 256, 0, stream>>>(HG, Ocur, c_mih_h, c_mih_l, c_mhh_h, c_mhh_l,
                                       mGbih, mGbhh, Onxt, GG);
    { float* tt = Ocur; Ocur = Onxt; Onxt = tt; }
  }

  // ---- fused lin2 + final ----
  k_final<<<(GG+3)/4, 256, 0, stream>>>(Ocur, WEFF, (float*)d_out);
}

// Round 10
// 1238.886 us; speedup vs baseline: 1.0908x; 1.0908x over previous
//
#include <hip/hip_runtime.h>
#include <math.h>

#define NN 50000
#define EE 800000
#define GG 2000
#define HH 128
#define FN 64
#define FE 16

typedef short bf16x8 __attribute__((ext_vector_type(8)));
typedef float f32x4  __attribute__((ext_vector_type(4)));

// ---------------- device helpers ----------------
__device__ __forceinline__ float leakyf(float v){ return v>=0.f ? v : 0.01f*v; }
__device__ __forceinline__ float eluf(float v){ return v>0.f ? v : expm1f(v); }
__device__ __forceinline__ float sigmf(float v){ return 1.f/(1.f+__expf(-v)); }
__device__ __forceinline__ float tanh_fast(float x){
  float ax = fabsf(x);
  float e = __expf(-2.f*ax);
  float t = (1.f - e)/(1.f + e);
  return x>=0.f ? t : -t;
}
__device__ __forceinline__ int rdl(int v, int l){ return __builtin_amdgcn_readlane(v, l); }
__device__ __forceinline__ float rdlf(float v, int l){
  return __int_as_float(__builtin_amdgcn_readlane(__float_as_int(v), l));
}
__device__ __forceinline__ float wsum(float v){
#pragma unroll
  for(int m=32;m>=1;m>>=1) v += __shfl_xor(v,m,64);
  return v;
}
__device__ __forceinline__ float wsum16(float v){
#pragma unroll
  for(int m=8;m>=1;m>>=1) v += __shfl_xor(v,m,64);
  return v;
}
__device__ __forceinline__ float wmax64(float v){
#pragma unroll
  for(int m=32;m>=1;m>>=1) v = fmaxf(v,__shfl_xor(v,m,64));
  return v;
}

__device__ __forceinline__ f32x4 mfma16(bf16x8 a, bf16x8 b, f32x4 c){
  return __builtin_amdgcn_mfma_f32_16x16x32_bf16(a, b, c, 0, 0, 0);
}

// split 8 consecutive fp32 into bf16 hi (truncate) + bf16 lo (truncate of residual)
__device__ __forceinline__ void splitbf8(const float* p, bf16x8 &hi, bf16x8 &lo){
  float4 u = *(const float4*)p;
  float4 v = *(const float4*)(p+4);
  float f[8] = {u.x,u.y,u.z,u.w,v.x,v.y,v.z,v.w};
#pragma unroll
  for(int i=0;i<8;i++){
    unsigned b = __float_as_uint(f[i]);
    unsigned ht = b & 0xFFFF0000u;
    hi[i] = (short)(b >> 16);
    float r = f[i] - __uint_as_float(ht);
    lo[i] = (short)(__float_as_uint(r) >> 16);
  }
}

// ---------------- weight pre-split segment map (elements) ----------------
#define CV_LIN1   0        // 128x64
#define CV_G1X    8192     // 128x128 from glin1W (ld 144, cols 0..127)
#define CV_G2     24576    // 128x128
#define CV_ALIN   40960    // 2x128x128
#define CV_MOL    73728    // 128x128
#define CV_G0IH   90112    // 384x128
#define CV_G0HH   139264
#define CV_AIH    188416   // 2x384x128
#define CV_AHH    286720
#define CV_MIH    385024
#define CV_MHH    434176
#define CV_GE     483328   // 128x16: glin1W edge-part (cols 128..143)
#define CV_TOT2   485376

__global__ void k_convw2(const float* __restrict__ lin1W, const float* __restrict__ glin1W,
                         const float* __restrict__ glin2W, const float* __restrict__ aLinW,
                         const float* __restrict__ aGWih, const float* __restrict__ aGWhh,
                         const float* __restrict__ mLinW, const float* __restrict__ mGWih,
                         const float* __restrict__ mGWhh, const float* __restrict__ g0Wih,
                         const float* __restrict__ g0Whh,
                         short* __restrict__ hi, short* __restrict__ lo){
  int i = blockIdx.x*256 + threadIdx.x;
  if(i >= CV_TOT2) return;
  float v;
  if(i < CV_G1X){            v = lin1W[i];
  } else if(i < CV_G2){      int idx = i - CV_G1X; v = glin1W[(size_t)(idx>>7)*144 + (idx&127)];
  } else if(i < CV_ALIN){    v = glin2W[i - CV_G2];
  } else if(i < CV_MOL){     v = aLinW[i - CV_ALIN];
  } else if(i < CV_G0IH){    v = mLinW[i - CV_MOL];
  } else if(i < CV_G0HH){    v = g0Wih[i - CV_G0IH];
  } else if(i < CV_AIH){     v = g0Whh[i - CV_G0HH];
  } else if(i < CV_AHH){     v = aGWih[i - CV_AIH];
  } else if(i < CV_MIH){     v = aGWhh[i - CV_AHH];
  } else if(i < CV_MHH){     v = mGWih[i - CV_MIH];
  } else if(i < CV_GE){      v = mGWhh[i - CV_MHH];
  } else {                   int idx = i - CV_GE; v = glin1W[(size_t)(idx>>4)*144 + 128 + (idx&15)];
  }
  unsigned b = __float_as_uint(v);
  unsigned ht = b & 0xFFFF0000u;
  hi[i] = (short)(b >> 16);
  float r = v - __uint_as_float(ht);
  lo[i] = (short)(__float_as_uint(r) >> 16);
}

// ---------------- CSR build (fused: both edge sorts + graph counts) ----------------
__global__ void k_count_all(const int* __restrict__ esrc, const int* __restrict__ edst,
                            const int* __restrict__ batch,
                            int* __restrict__ degd, int* __restrict__ degs,
                            int* __restrict__ gcnt){
  int i = blockIdx.x*256 + threadIdx.x;
  if(i < EE){
    atomicAdd(&degd[edst[i]], 1);
    atomicAdd(&degs[esrc[i]], 1);
  }
  if(i < NN) atomicAdd(&gcnt[batch[i]], 1);
}

__global__ void k_scan3(const int* __restrict__ degd, const int* __restrict__ degs,
                        const int* __restrict__ gcnt,
                        int* __restrict__ eoff, int* __restrict__ soff, int* __restrict__ goff){
  __shared__ int part[1024];
  const int* cnt; int* off; int n;
  if(blockIdx.x == 0){ cnt = degd; off = eoff; n = NN; }
  else if(blockIdx.x == 1){ cnt = degs; off = soff; n = NN; }
  else { cnt = gcnt; off = goff; n = GG; }
  int t = threadIdx.x;
  int C = (n + 1023) >> 10;
  int lo = t*C, hic = min(lo + C, n);
  int s = 0;
  for(int i=lo;i<hic;i++) s += cnt[i];
  part[t] = s;
  __syncthreads();
  for(int o=1;o<1024;o<<=1){
    int v = (t>=o) ? part[t-o] : 0;
    __syncthreads();
    part[t] += v;
    __syncthreads();
  }
  int base = part[t] - s;
  int run = base;
  for(int i=lo;i<hic;i++){ run += cnt[i]; off[i+1] = run; }
  if(t==0) off[0] = 0;
}

// scatter + flatten: src-sorted order p gets direct arrays (no chained indirection)
// and EA repacked to bf16 hi|lo (32 shorts/edge). Scattered WRITES (fire-and-forget)
// replace what were alpha's latency-bound scattered READS.
__global__ void k_scatter2(const int* __restrict__ esrc, const int* __restrict__ edst,
                           const int* __restrict__ eoff, const int* __restrict__ soff,
                           int* __restrict__ curd, int* __restrict__ curs,
                           int* __restrict__ esrcS, const float* __restrict__ EA,
                           int* __restrict__ esrcO, int* __restrict__ edstO,
                           int* __restrict__ epermO, short* __restrict__ EAs){
  int e = blockIdx.x*256 + threadIdx.x;
  if(e < EE){
    int d = edst[e];
    int pos = eoff[d] + atomicAdd(&curd[d], 1);
    int s = esrc[e];
    esrcS[pos] = s;
    int p = soff[s] + atomicAdd(&curs[s], 1);
    esrcO[p] = s;
    edstO[p] = d;
    epermO[p] = pos;
    bf16x8 h0, l0, h1, l1;
    splitbf8(&EA[(size_t)e*FE], h0, l0);
    splitbf8(&EA[(size_t)e*FE + 8], h1, l1);
    short* dst = &EAs[(size_t)p*32];
    *(bf16x8*)(dst)      = h0;
    *(bf16x8*)(dst + 8)  = h1;
    *(bf16x8*)(dst + 16) = l0;
    *(bf16x8*)(dst + 24) = l1;
  }
}

// ---------------- MFMA projection + fused row-dots ----------------
template<int ACT, int K, int NDOT>
__global__ __launch_bounds__(256) void k_proj_mfma(const float* __restrict__ A,
                                                   const short* __restrict__ Whi,
                                                   const short* __restrict__ Wlo,
                                                   const float* __restrict__ bias,
                                                   float* __restrict__ C, int M,
                                                   const float* __restrict__ u,
                                                   const float* __restrict__ v,
                                                   float* __restrict__ douta,
                                                   float* __restrict__ doutb){
  const int wave = threadIdx.x >> 6, lane = threadIdx.x & 63;
  const int m0 = blockIdx.x*64 + wave*16;
  const int lr = lane & 15, kg = lane >> 4;
  f32x4 acc[8];
#pragma unroll
  for(int t=0;t<8;t++) acc[t] = (f32x4){0.f,0.f,0.f,0.f};

  int arow = m0 + lr;
  int ar = arow < M ? arow : (M-1);

#pragma unroll
  for(int ks=0;ks<K;ks+=32){
    const int kb = ks + kg*8;
    bf16x8 ahi, alo;
    splitbf8(&A[(size_t)ar*K + kb], ahi, alo);
#pragma unroll
    for(int t=0;t<8;t++){
      const bf16x8 bh = *(const bf16x8*)&Whi[(size_t)(t*16+lr)*K + kb];
      const bf16x8 bl = *(const bf16x8*)&Wlo[(size_t)(t*16+lr)*K + kb];
      acc[t] = mfma16(ahi, bh, acc[t]);
      acc[t] = mfma16(ahi, bl, acc[t]);
      acc[t] = mfma16(alo, bh, acc[t]);
    }
  }

  float p1[4] = {0.f,0.f,0.f,0.f};
  float p2[4] = {0.f,0.f,0.f,0.f};
#pragma unroll
  for(int t=0;t<8;t++){
    int c = t*16 + lr;
    float ut = (NDOT>=1) ? u[c] : 0.f;
    float vt = (NDOT>=2) ? v[c] : 0.f;
#pragma unroll
    for(int r=0;r<4;r++){
      int m = m0 + kg*4 + r;
      float val = acc[t][r];
      if(ACT==1) val = leakyf(val + bias[c]);
      if(m < M) C[(size_t)m*HH + c] = val;
      if(NDOT>=1) p1[r] += val*ut;
      if(NDOT>=2) p2[r] += val*vt;
    }
  }
  if(NDOT>=1){
#pragma unroll
    for(int r=0;r<4;r++){
      float s1 = wsum16(p1[r]);
      int m = m0 + kg*4 + r;
      if(lr==0 && m < M) douta[m] = s1;
      if(NDOT>=2){
        float s2 = wsum16(p2[r]);
        if(lr==0 && m < M) doutb[m] = s2;
      }
    }
  }
}

// ---------------- fused MFMA GRUCell v3: LDS-staged weights (r7-verified) ----------------
__global__ __launch_bounds__(256) void k_gru_mfma(const float* __restrict__ MSG,
                                                  const float* __restrict__ X,
                                                  const short* __restrict__ WIhi,
                                                  const short* __restrict__ WIlo,
                                                  const short* __restrict__ WHhi,
                                                  const short* __restrict__ WHlo,
                                                  const float* __restrict__ bih,
                                                  const float* __restrict__ bhh,
                                                  float* __restrict__ XOUT, int M){
  __shared__ short LW[12*16*128];
  const int tid = threadIdx.x;
  const int wave = tid >> 6, lane = tid & 63;
  const int m0 = blockIdx.x*64 + wave*16;
  const int lr = lane & 15, kg = lane >> 4;
  int arow = m0 + lr;
  int ar = arow < M ? arow : (M-1);

  bf16x8 mh[4], ml[4], xh[4], xl[4];
#pragma unroll
  for(int ks=0;ks<4;ks++){
    splitbf8(&MSG[(size_t)ar*HH + ks*32 + kg*8], mh[ks], ml[ks]);
    splitbf8(&X  [(size_t)ar*HH + ks*32 + kg*8], xh[ks], xl[ks]);
  }

  const int srow = tid >> 4;
  const int scb  = tid & 15;
  const int sdst = srow*128 + ((scb ^ (srow & 7))*8);
  const size_t sgoff = (size_t)srow*HH + scb*8;

#pragma unroll 1
  for(int t=0;t<8;t++){
#pragma unroll
    for(int r=0;r<12;r++){
      const short* mat = (r<3) ? WIhi : (r<6) ? WHhi : (r<9) ? WIlo : WHlo;
      const int g = (r % 3);
      const short* src = mat + (size_t)(g*128 + t*16)*HH + sgoff;
      *(bf16x8*)&LW[r*2048 + sdst] = *(const bf16x8*)src;
    }
    __syncthreads();

    f32x4 aIr = (f32x4){0.f,0.f,0.f,0.f}, aIz = aIr, aIn = aIr;
    f32x4 aHr = aIr, aHz = aIr, aHn = aIr;
#pragma unroll
    for(int ks=0;ks<4;ks++){
      const int cb = ks*4 + kg;
      const int rb = lr*128 + ((cb ^ (lr & 7))*8);
      bf16x8 bIrh = *(const bf16x8*)&LW[ 0*2048 + rb];
      bf16x8 bIzh = *(const bf16x8*)&LW[ 1*2048 + rb];
      bf16x8 bInh = *(const bf16x8*)&LW[ 2*2048 + rb];
      bf16x8 bHrh = *(const bf16x8*)&LW[ 3*2048 + rb];
      bf16x8 bHzh = *(const bf16x8*)&LW[ 4*2048 + rb];
      bf16x8 bHnh = *(const bf16x8*)&LW[ 5*2048 + rb];
      bf16x8 bIrl = *(const bf16x8*)&LW[ 6*2048 + rb];
      bf16x8 bIzl = *(const bf16x8*)&LW[ 7*2048 + rb];
      bf16x8 bInl = *(const bf16x8*)&LW[ 8*2048 + rb];
      bf16x8 bHrl = *(const bf16x8*)&LW[ 9*2048 + rb];
      bf16x8 bHzl = *(const bf16x8*)&LW[10*2048 + rb];
      bf16x8 bHnl = *(const bf16x8*)&LW[11*2048 + rb];
      aIr = mfma16(mh[ks], bIrh, aIr); aIr = mfma16(mh[ks], bIrl, aIr); aIr = mfma16(ml[ks], bIrh, aIr);
      aIz = mfma16(mh[ks], bIzh, aIz); aIz = mfma16(mh[ks], bIzl, aIz); aIz = mfma16(ml[ks], bIzh, aIz);
      aIn = mfma16(mh[ks], bInh, aIn); aIn = mfma16(mh[ks], bInl, aIn); aIn = mfma16(ml[ks], bInh, aIn);
      aHr = mfma16(xh[ks], bHrh, aHr); aHr = mfma16(xh[ks], bHrl, aHr); aHr = mfma16(xl[ks], bHrh, aHr);
      aHz = mfma16(xh[ks], bHzh, aHz); aHz = mfma16(xh[ks], bHzl, aHz); aHz = mfma16(xl[ks], bHzh, aHz);
      aHn = mfma16(xh[ks], bHnh, aHn); aHn = mfma16(xh[ks], bHnl, aHn); aHn = mfma16(xl[ks], bHnh, aHn);
    }

    const int c = t*16 + lr;
    const float bir = bih[c], biz = bih[c+HH], bin = bih[c+2*HH];
    const float bhr = bhh[c], bhz = bhh[c+HH], bhn = bhh[c+2*HH];
#pragma unroll
    for(int r=0;r<4;r++){
      int mm = m0 + kg*4 + r;
      if(mm < M){
        float ir = aIr[r]+bir, iz = aIz[r]+biz, in_ = aIn[r]+bin;
        float hr = aHr[r]+bhr, hz = aHz[r]+bhz, hn = aHn[r]+bhn;
        float rr = sigmf(ir + hr);
        float z  = sigmf(iz + hz);
        float ng = tanh_fast(in_ + rr*hn);
        float hp = X[(size_t)mm*HH + c];
        XOUT[(size_t)mm*HH + c] = fmaxf((1.f - z)*ng + z*hp, 0.f);
      }
    }
    __syncthreads();
  }
}

// ---------------- GATEConv edge alpha v5: flat arrays, 1 tile/wave ----------------
// R9 diagnosis: alpha4 latency-bound on eord->esrc->XP chain at 6 waves/SIMD.
// Fix: (1) esrcO/edstO/epermO direct arrays (chain depth 3 -> 1);
// (2) EA pre-split to bf16 in scatter -> A-frag is ONE coalesced 16B load;
// (3) one 16-edge tile per wave (50000 waves, ~49/SIMD TLP).
// Math identical to verified alpha4: MFMA1 [hi|lo]x[whi|whi], MFMA2 [hi|0]x[wlo|..].
__global__ __launch_bounds__(256) void k_gate_alpha5(const float* __restrict__ XP,
                                                     const short* __restrict__ EAs,
                                                     const int* __restrict__ esrcO,
                                                     const int* __restrict__ edstO,
                                                     const int* __restrict__ epermO,
                                                     const short* __restrict__ GEhi,
                                                     const short* __restrict__ GElo,
                                                     const float* __restrict__ attl,
                                                     const float* __restrict__ RD,
                                                     float* __restrict__ ALPHA){
  const int lane = threadIdx.x & 63;
  const int tile = (blockIdx.x*256 + threadIdx.x) >> 6;
  if(tile >= EE/16) return;
  const int p0 = tile*16;
  const int lr = lane & 15, kg = lane >> 4;

  // A-frag: one 16B coalesced load from pre-split EAs
  const short* eap = &EAs[(size_t)(p0+lr)*32 + (kg>=2 ? 16 : 0) + (kg&1)*8];
  bf16x8 A1 = *(const bf16x8*)eap;
  bf16x8 A2 = A1;
  if(kg >= 2){
#pragma unroll
    for(int i=0;i<8;i++) A2[i] = 0;
  }

  // srcR: one broadcast int4 load
  int4 sr4 = *(const int4*)&esrcO[p0 + kg*4];
  int srcR[4] = {sr4.x, sr4.y, sr4.z, sr4.w};

  // B-frags (L1-resident, 8KB total across wave)
  bf16x8 B1[8], B2[8];
  float at[8];
#pragma unroll
  for(int t=0;t<8;t++){
    const int col = t*16 + lr;
    B1[t] = *(const bf16x8*)&GEhi[col*16 + (kg&1)*8];
    B2[t] = *(const bf16x8*)&GElo[col*16 + (kg&1)*8];
    at[t] = attl[col];
  }

  float p[4] = {0.f,0.f,0.f,0.f};
#pragma unroll
  for(int t=0;t<8;t++){
    f32x4 acc = (f32x4){0.f,0.f,0.f,0.f};
    acc = mfma16(A2, B2[t], acc);
    acc = mfma16(A1, B1[t], acc);
    const int c = t*16 + lr;
#pragma unroll
    for(int r=0;r<4;r++){
      float xp = XP[(size_t)srcR[r]*HH + c];
      p[r] += leakyf(acc[r] + xp) * at[t];
    }
  }
#pragma unroll
  for(int r=0;r<4;r++){
    float s = wsum16(p[r]);
    if(lr == 0){
      const int j = p0 + kg*4 + r;
      ALPHA[epermO[j]] = leakyf(s + RD[edstO[j]]);
    }
  }
}

// ---------------- segment softmax -> normalized edge weights ----------------
template<int MODE>
__global__ void k_softmaxw(const int* __restrict__ off, const int* __restrict__ items,
                           const float* __restrict__ AIN, const float* __restrict__ A1,
                           const float* __restrict__ A2, float* __restrict__ WOUT, int nseg){
  int w = (blockIdx.x*blockDim.x + threadIdx.x) >> 6;
  int lane = threadIdx.x & 63;
  if(w >= nseg) return;
  int s0 = off[w], s1 = off[w+1];
  int n = s1 - s0;
  float a2 = (MODE==0) ? 0.f : A2[w];

  if(n <= 64){
    float a = -INFINITY;
    int i = s0 + lane;
    if(lane < n){
      if(MODE==0) a = AIN[i];
      else if(MODE==1) a = leakyf(A1[items[i]] + a2);
      else a = leakyf(A1[i] + a2);
    }
    float m = wmax64(a);
    float e = (lane < n) ? __expf(a - m) : 0.f;
    float s = wsum(e);
    if(lane < n) WOUT[i] = e/(s + 1e-16f);
    return;
  }

  float m = -INFINITY;
  for(int i=s0+lane;i<s1;i+=64){
    float a;
    if(MODE==0) a = AIN[i];
    else if(MODE==1) a = leakyf(A1[items[i]] + a2);
    else a = leakyf(A1[i] + a2);
    m = fmaxf(m, a);
  }
  m = wmax64(m);

  float s = 0.f;
  for(int i=s0+lane;i<s1;i+=64){
    float a;
    if(MODE==0) a = AIN[i];
    else if(MODE==1) a = leakyf(A1[items[i]] + a2);
    else a = leakyf(A1[i] + a2);
    s += __expf(a - m);
  }
  s = wsum(s);
  float inv = 1.f/(s + 1e-16f);

  for(int i=s0+lane;i<s1;i+=64){
    float a;
    if(MODE==0) a = AIN[i];
    else if(MODE==1) a = leakyf(A1[items[i]] + a2);
    else a = leakyf(A1[i] + a2);
    WOUT[i] = __expf(a - m)*inv;
  }
}

// ---------------- weighted row gather: OUT[w] = elu(sum_i W[i]*XSrc[it_i] + bias) ----------------
__global__ void k_gather(const int* __restrict__ off, const int* __restrict__ items,
                         const float* __restrict__ W, const float* __restrict__ XSrc,
                         const float* __restrict__ bias, float* __restrict__ OUT, int nseg){
  int w = (blockIdx.x*blockDim.x + threadIdx.x) >> 6;
  int lane = threadIdx.x & 63;
  if(w >= nseg) return;
  int s0 = off[w], s1 = off[w+1];
  float hx = 0.f, hy = 0.f;

  for(int c0=s0;c0<s1;c0+=64){
    int n = min(64, s1-c0);
    int it = 0; float wg = 0.f;
    if(lane < n){
      int i = c0 + lane;
      it = items ? items[i] : i;
      wg = W[i];
    }
#pragma unroll 16
    for(int j=0;j<n;j++){
      int itj = rdl(it, j);
      float wj = rdlf(wg, j);
      float2 xv = *(const float2*)&XSrc[(size_t)itj*HH + 2*lane];
      hx += wj*xv.x;
      hy += wj*xv.y;
    }
  }
  float2 bv = *(const float2*)&bias[2*lane];
  float2 o;
  o.x = eluf(hx + bv.x);
  o.y = eluf(hy + bv.y);
  *(float2*)&OUT[(size_t)w*HH + 2*lane] = o;
}

// ---------------- small per-row kernels ----------------
__global__ void k_dot2(const float* __restrict__ X, const float* __restrict__ u,
                       float* __restrict__ a, int M){
  int w = (blockIdx.x*blockDim.x + threadIdx.x) >> 6;
  int lane = threadIdx.x & 63;
  if(w >= M) return;
  float2 x = *(const float2*)&X[(size_t)w*HH + 2*lane];
  float2 uu = *(const float2*)&u[2*lane];
  float p = x.x*uu.x + x.y*uu.y;
  p = wsum(p);
  if(lane==0) a[w] = p;
}

__global__ void k_ginit(const int* __restrict__ goff, const float* __restrict__ X,
                        float* __restrict__ OUT){
  int g = (blockIdx.x*blockDim.x + threadIdx.x) >> 6;
  int lane = threadIdx.x & 63;
  if(g >= GG) return;
  int s0 = goff[g], s1 = goff[g+1];
  float hx=0.f, hy=0.f;
  for(int n=s0;n<s1;n++){
    float2 xv = *(const float2*)&X[(size_t)n*HH + 2*lane];
    hx += xv.x; hy += xv.y;
  }
  float2 o;
  o.x = fmaxf(hx, 0.f);
  o.y = fmaxf(hy, 0.f);
  *(float2*)&OUT[(size_t)g*HH + 2*lane] = o;
}

// weff[c] = finW·lin2W[:,c]; weff[128] = lin2b·finW + finb; weff[256+c] = mAttD·mLinW[:,c]
__global__ void k_weff(const float* __restrict__ lin2W, const float* __restrict__ lin2b,
                       const float* __restrict__ finW, const float* __restrict__ finb,
                       const float* __restrict__ mLinW, const float* __restrict__ mAttD,
                       float* __restrict__ weff){
  int c = threadIdx.x;
  float s = 0.f, q = 0.f;
  for(int j=0;j<HH;j++){
    s += finW[j]*lin2W[(size_t)j*HH + c];
    q += mAttD[j]*mLinW[(size_t)j*HH + c];
  }
  weff[c] = s;
  weff[256 + c] = q;
  if(c==0){
    float bb = finb[0];
    for(int j=0;j<HH;j++) bb += lin2b[j]*finW[j];
    weff[HH] = bb;
  }
}

__global__ void k_final(const float* __restrict__ OUT, const float* __restrict__ weff,
                        float* __restrict__ y){
  int g = (blockIdx.x*blockDim.x + threadIdx.x) >> 6;
  int lane = threadIdx.x & 63;
  if(g >= GG) return;
  float2 ov = *(const float2*)&OUT[(size_t)g*HH + 2*lane];
  float2 wv = *(const float2*)&weff[2*lane];
  float p = ov.x*wv.x + ov.y*wv.y;
  p = wsum(p);
  if(lane==0) y[g] = sigmf(p + weff[HH]);
}

// ---------------- host ----------------
extern "C" void kernel_launch(void* const* d_in, const int* in_sizes, int n_in,
                              void* d_out, int out_size, void* d_ws, size_t ws_size,
                              hipStream_t stream){
  const float* in_x   = (const float*)d_in[0];
  const int*   eidx   = (const int*)d_in[1];
  const float* ea     = (const float*)d_in[2];
  const int*   batch  = (const int*)d_in[3];
  const float* lin1W  = (const float*)d_in[4];
  const float* lin1b  = (const float*)d_in[5];
  const float* gattl  = (const float*)d_in[6];
  const float* gattr  = (const float*)d_in[7];
  const float* glin1W = (const float*)d_in[8];
  const float* glin2W = (const float*)d_in[9];
  const float* gbias  = (const float*)d_in[10];
  const float* g0Wih  = (const float*)d_in[11];
  const float* g0Whh  = (const float*)d_in[12];
  const float* g0bih  = (const float*)d_in[13];
  const float* g0bhh  = (const float*)d_in[14];
  const float* aLinW  = (const float*)d_in[15];
  const float* aAttS  = (const float*)d_in[16];
  const float* aAttD  = (const float*)d_in[17];
  const float* aBias  = (const float*)d_in[18];
  const float* aGWih  = (const float*)d_in[19];
  const float* aGWhh  = (const float*)d_in[20];
  const float* aGbih  = (const float*)d_in[21];
  const float* aGbhh  = (const float*)d_in[22];
  const float* mLinW  = (const float*)d_in[23];
  const float* mAttS  = (const float*)d_in[24];
  const float* mAttD  = (const float*)d_in[25];
  const float* mBias  = (const float*)d_in[26];
  const float* mGWih  = (const float*)d_in[27];
  const float* mGWhh  = (const float*)d_in[28];
  const float* mGbih  = (const float*)d_in[29];
  const float* mGbhh  = (const float*)d_in[30];
  const float* lin2W  = (const float*)d_in[31];
  const float* lin2b  = (const float*)d_in[32];
  const float* finW   = (const float*)d_in[33];
  const float* finb   = (const float*)d_in[34];

  const int* esrc0 = eidx;
  const int* edst0 = eidx + EE;

  char* w = (char*)d_ws;
  size_t o = 0;
  auto alloc = [&](size_t bytes)->void*{
    void* p = w + o;
    o = (o + bytes + 255) & ~(size_t)255;
    return p;
  };
  float* X    = (float*)alloc((size_t)NN*HH*4);
  float* XB   = (float*)alloc((size_t)NN*HH*4);
  float* XS   = (float*)alloc((size_t)NN*HH*4);
  float* MSG  = (float*)alloc((size_t)NN*HH*4);
  float* XP   = (float*)alloc((size_t)NN*HH*4);
  float* ALPHA= (float*)alloc((size_t)EE*4);
  float* S1   = (float*)alloc((size_t)NN*4);
  float* S2   = (float*)alloc((size_t)NN*4);
  float* ADSTG= (float*)alloc((size_t)GG*4);
  float* OUTg = (float*)alloc((size_t)GG*HH*4);
  float* OUTb = (float*)alloc((size_t)GG*HH*4);
  float* HG   = (float*)alloc((size_t)GG*HH*4);
  float* WEFF = (float*)alloc(512*4);
  short* cWhi = (short*)alloc((size_t)CV_TOT2*2);
  short* cWlo = (short*)alloc((size_t)CV_TOT2*2);
  int* zeroreg= (int*)alloc((size_t)(4*NN + 2048)*4);
  int* degd = zeroreg;
  int* degs = zeroreg + NN;
  int* curd = zeroreg + 2*NN;
  int* curs = zeroreg + 3*NN;
  int* gcnt = zeroreg + 4*NN;
  int* eoff = (int*)alloc((size_t)(NN+1)*4);
  int* soff = (int*)alloc((size_t)(NN+1)*4);
  int* goff = (int*)alloc((size_t)(GG+1)*4);
  int* esrcS= (int*)alloc((size_t)EE*4);
  int* esrcO= (int*)alloc((size_t)EE*4);
  int* edstO= (int*)alloc((size_t)EE*4);
  int* epermO=(int*)alloc((size_t)EE*4);
  short* EAs = (short*)alloc((size_t)EE*32*2);

  const short* c_lin1_h = cWhi + CV_LIN1; const short* c_lin1_l = cWlo + CV_LIN1;
  const short* c_g1x_h  = cWhi + CV_G1X;  const short* c_g1x_l  = cWlo + CV_G1X;
  const short* c_g2_h   = cWhi + CV_G2;   const short* c_g2_l   = cWlo + CV_G2;
  const short* c_mol_h  = cWhi + CV_MOL;  const short* c_mol_l  = cWlo + CV_MOL;
  const short* c_g0ih_h = cWhi + CV_G0IH; const short* c_g0ih_l = cWlo + CV_G0IH;
  const short* c_g0hh_h = cWhi + CV_G0HH; const short* c_g0hh_l = cWlo + CV_G0HH;
  const short* c_mih_h  = cWhi + CV_MIH;  const short* c_mih_l  = cWlo + CV_MIH;
  const short* c_mhh_h  = cWhi + CV_MHH;  const short* c_mhh_l  = cWlo + CV_MHH;
  const short* c_ge_h   = cWhi + CV_GE;   const short* c_ge_l   = cWlo + CV_GE;

  // ---- weight pre-split + fused final-layer vectors ----
  k_convw2<<<(CV_TOT2+255)/256, 256, 0, stream>>>(lin1W, glin1W, glin2W, aLinW, aGWih, aGWhh,
                                                  mLinW, mGWih, mGWhh, g0Wih, g0Whh, cWhi, cWlo);
  k_weff<<<1, 128, 0, stream>>>(lin2W, lin2b, finW, finb, mLinW, mAttD, WEFF);

  // ---- CSR build (dst-sorted + src-sorted-flattened + graph offsets) ----
  hipMemsetAsync(zeroreg, 0, (size_t)(4*NN + 2048)*4, stream);
  k_count_all<<<EE/256, 256, 0, stream>>>(esrc0, edst0, batch, degd, degs, gcnt);
  k_scan3<<<3, 1024, 0, stream>>>(degd, degs, gcnt, eoff, soff, goff);
  k_scatter2<<<EE/256, 256, 0, stream>>>(esrc0, edst0, eoff, soff, curd, curs,
                                         esrcS, ea, esrcO, edstO, epermO, EAs);

  const int gN = (NN + 63)/64;   // 782
  const int gG = (GG + 63)/64;   // 32

  // ---- input projection (+ fused S1 = X·gattr) ----
  k_proj_mfma<1,64,1><<<gN, 256, 0, stream>>>(in_x, c_lin1_h, c_lin1_l, lin1b, X, NN,
                                              gattr, nullptr, S1, nullptr);

  // ---- GATEConv ----
  k_proj_mfma<0,128,0><<<gN, 256, 0, stream>>>(X, c_g1x_h, c_g1x_l, nullptr, XP, NN,
                                               nullptr, nullptr, nullptr, nullptr);
  k_proj_mfma<0,128,0><<<gN, 256, 0, stream>>>(X, c_g2_h, c_g2_l, nullptr, XS, NN,
                                               nullptr, nullptr, nullptr, nullptr);
  k_gate_alpha5<<<(EE/16 + 3)/4, 256, 0, stream>>>(XP, EAs, esrcO, edstO, epermO,
                                                   c_ge_h, c_ge_l, gattl, S1, ALPHA);
  k_softmaxw<0><<<(NN+3)/4, 256, 0, stream>>>(eoff, nullptr, ALPHA, nullptr, nullptr, ALPHA, NN);
  k_gather<<<(NN+3)/4, 256, 0, stream>>>(eoff, esrcS, ALPHA, XS, gbias, MSG, NN);
  k_gru_mfma<<<gN, 256, 0, stream>>>(MSG, X, c_g0ih_h, c_g0ih_l, c_g0hh_h, c_g0hh_l,
                                     g0bih, g0bhh, XB, NN);
  { float* t = X; X = XB; XB = t; }

  // ---- atom GATConv layers ----
  for(int l=0;l<2;l++){
    const short* c_a_h   = cWhi + CV_ALIN + (size_t)l*HH*HH;
    const short* c_a_l   = cWlo + CV_ALIN + (size_t)l*HH*HH;
    const short* c_aih_h = cWhi + CV_AIH + (size_t)l*3*HH*HH;
    const short* c_aih_l = cWlo + CV_AIH + (size_t)l*3*HH*HH;
    const short* c_ahh_h = cWhi + CV_AHH + (size_t)l*3*HH*HH;
    const short* c_ahh_l = cWlo + CV_AHH + (size_t)l*3*HH*HH;
    const float* asl  = aAttS + (size_t)l*HH;
    const float* adl  = aAttD + (size_t)l*HH;
    const float* bl   = aBias + (size_t)l*HH;
    const float* bi   = aGbih + (size_t)l*3*HH;
    const float* bh   = aGbhh + (size_t)l*3*HH;
    k_proj_mfma<0,128,2><<<gN, 256, 0, stream>>>(X, c_a_h, c_a_l, nullptr, XS, NN,
                                                 asl, adl, S1, S2);
    k_softmaxw<1><<<(NN+3)/4, 256, 0, stream>>>(eoff, esrcS, nullptr, S1, S2, ALPHA, NN);
    k_gather<<<(NN+3)/4, 256, 0, stream>>>(eoff, esrcS, ALPHA, XS, bl, MSG, NN);
    k_gru_mfma<<<gN, 256, 0, stream>>>(MSG, X, c_aih_h, c_aih_l, c_ahh_h, c_ahh_l, bi, bh, XB, NN);
    { float* t = X; X = XB; XB = t; }
  }

  // ---- molecule readout ----
  k_ginit<<<(GG+3)/4, 256, 0, stream>>>(goff, X, OUTg);
  k_proj_mfma<0,128,1><<<gN, 256, 0, stream>>>(X, c_mol_h, c_mol_l, nullptr, XS, NN,
                                               mAttS, nullptr, S1, nullptr);

  float* Ocur = OUTg;
  float* Onxt = OUTb;
  for(int t=0;t<3;t++){
    k_dot2<<<(GG+3)/4, 256, 0, stream>>>(Ocur, WEFF+256, ADSTG, GG);
    k_softmaxw<2><<<(GG+3)/4, 256, 0, stream>>>(goff, nullptr, nullptr, S1, ADSTG, ALPHA, GG);
    k_gather<<<(GG+3)/4, 256, 0, stream>>>(goff, nullptr, ALPHA, XS, mBias, HG, GG);
    k_gru_mfma<<<gG, 256, 0, stream>>>(HG, Ocur, c_mih_h, c_mih_l, c_mhh_h, c_mhh_l,
                                       mGbih, mGbhh, Onxt, GG);
    { float* tt = Ocur; Ocur = Onxt; Onxt = tt; }
  }

  // ---- fused lin2 + final ----
  k_final<<<(GG+3)/4, 256, 0, stream>>>(Ocur, WEFF, (float*)d_out);
}